// Round 12
// baseline (492.096 us; speedup 1.0000x reference)
//
#include <hip/hip_runtime.h>

// PointNetKnnInterpolator on MI355X (gfx950).
// h = [x[x_idx], pos_x[x_idx]-pos_y[y_idx]]  (400000 x 67)
// net = relu(h)@W0a+b0a ; dx = relu(net)@W1a+b1a ; h2 = h@Wsa + dx
// net2 = relu(h2)@W0b+b0b ; h3 = h2 + relu(net2)@W1b+b1b
// out[y] = max over 8 consecutive rows of h3.
//
// R12 = R11 with the cvt_pkrtz type fixed (builtin returns __fp16x2; bit-cast
// to our _Float16x2). R11 scheme recap (on R10's transposed formulation:
// actT = WT@actT, weights=A from LDS, activations=B in registers, PHI-permuted
// weight K so accumulators re-feed as B-frags with 12 VALU, no LDS):
//  - bias MFMAs removed: b1a/b0b init accumulators via broadcast ds_read_b128
//    from a 768B bias table; b1b added by 16 v_add before mm5.
//    NFRAG 60->48, MFMA 60->48, LDS 60->48KB/tile.
//  - epilogue LDS buffer eliminated: dr = n0 = lane bits 0-3, so segment-max
//    = 3 shfl_xor (1,2,4) on f16-packed accs, store from lanes n0&7==0.
//    LDS block 79.9->48.8 KB -> 3 blocks/CU = 24 waves/CU.
//  - depth-2 gather prefetch (idx -> row-data pipelined across iterations).
//  - 25000 = 4*6144 + 424: remainder as 5th round on wave (blockIdx%8) of
//    blocks 0..423 (~1% CU imbalance, keeps block-adjacent tile locality).

typedef _Float16 f16x8 __attribute__((ext_vector_type(8)));
typedef _Float16 f16x4 __attribute__((ext_vector_type(4)));
typedef _Float16 f16x2 __attribute__((ext_vector_type(2)));
typedef __fp16   fp16x2_n __attribute__((ext_vector_type(2)));  // builtin native
typedef float    f32x4 __attribute__((ext_vector_type(4)));

constexpr int NX     = 20000;
constexpr int NROWS  = 50000 * 8;    // NY * K
constexpr int NTILES = NROWS / 16;   // 25000
constexpr int NFRAG  = 48;           // g0:W0a 12, g1:Wsa 12, g2:W1a 8, g3:W0b 8, g4:W1b 8
constexpr int BW     = 8;            // waves per block
constexpr int BLOCK  = 64 * BW;      // 512
constexpr int GRID   = 768;          // 3 blocks/CU resident
constexpr int NWAVES = GRID * BW;    // 6144
constexpr int FULLR  = NTILES / NWAVES;        // 4 full rounds
constexpr int REM    = NTILES - FULLR * NWAVES; // 424 remainder tiles

__global__ void prep_x(const float* __restrict__ x, _Float16* __restrict__ x16) {
    const int i = blockIdx.x * blockDim.x + threadIdx.x;   // one float4 each
    if (i < NX * 16) {
        float4 v = ((const float4*)x)[i];
        f16x4 o = {(_Float16)v.x, (_Float16)v.y, (_Float16)v.z, (_Float16)v.w};
        *(f16x4*)(x16 + (size_t)i * 4) = o;
    }
}

// relu + repack accumulator (C-layout) into the two K=64 B-fragments.
// frag s element j <-> acc[t=2s+(j>>2)][r=j&3]  (matches PHI weight layout)
static __device__ __forceinline__ void pack_relu(const f32x4* A, f16x8* bf) {
#pragma unroll
    for (int s = 0; s < 2; ++s) {
        f16x8 r;
#pragma unroll
        for (int e = 0; e < 8; ++e) {
            float v = A[2 * s + (e >> 2)][e & 3];
            r[e] = (_Float16)(v > 0.0f ? v : 0.0f);
        }
        bf[s] = r;
    }
}

__global__ __launch_bounds__(BLOCK, 6)
void pointnet_fused(const _Float16* __restrict__ x16,
                    const float* __restrict__ pos_x,
                    const float* __restrict__ pos_y,
                    const int*   __restrict__ x_idx,
                    const float* __restrict__ W0a, const float* __restrict__ b0a,
                    const float* __restrict__ W1a, const float* __restrict__ b1a,
                    const float* __restrict__ Wsa,
                    const float* __restrict__ W0b, const float* __restrict__ b0b,
                    const float* __restrict__ W1b, const float* __restrict__ b1b,
                    float* __restrict__ out)
{
    __shared__ __align__(16) _Float16 bfrag[NFRAG * 64 * 8];   // 48 KiB
    __shared__ __align__(16) float bias_lds[3 * 64];           // 768 B: b1a,b0b,b1b

    const int tid = threadIdx.x;

    // ---- fill weight fragments (A operands, transposed; PHI-permuted K) ----
    // g0=W0a(identity K96, +b0a@k67) g1=Wsa(identity K96) g2=W1a g3=W0b g4=W1b (PHI K64)
    for (int p = tid; p < NFRAG * 64; p += BLOCK) {
        const int f = p >> 6, l = p & 63;
        const int q = l >> 4, n0 = l & 15;
        int grp, fl;
        if (f < 12)      { grp = 0; fl = f; }
        else if (f < 24) { grp = 1; fl = f - 12; }
        else if (f < 32) { grp = 2; fl = f - 24; }
        else if (f < 40) { grp = 3; fl = f - 32; }
        else             { grp = 4; fl = f - 40; }
        const int s = fl >> 2, t = fl & 3;
        const int col = t * 16 + n0;
        f16x8 v;
#pragma unroll
        for (int j = 0; j < 8; ++j) {
            const int k = 32 * s + 8 * q + j;
            float val = 0.0f;
            if (grp == 0)      val = (k < 67) ? W0a[k * 64 + col] : (k == 67 ? b0a[col] : 0.0f);
            else if (grp == 1) val = (k < 67) ? Wsa[k * 64 + col] : 0.0f;
            else {
                const float* W = (grp == 2) ? W1a : (grp == 3) ? W0b : W1b;
                const int row = 32 * s + 16 * (j >> 2) + 4 * q + (j & 3);  // PHI(k)
                val = W[row * 64 + col];
            }
            v[j] = (_Float16)val;
        }
        *(f16x8*)&bfrag[p * 8] = v;
    }
    if (tid < 192) {
        const int L = tid >> 6, i = tid & 63;
        const float* b = (L == 0) ? b1a : (L == 1) ? b0b : b1b;
        bias_lds[tid] = b[i];
    }
    __syncthreads();

    const int lane = tid & 63;
    const int wv   = tid >> 6;
    const int n0   = lane & 15;   // B col = data row (dr); A row m = out-feat%16
    const int q    = lane >> 4;

    const int gwave = blockIdx.x * BW + wv;
    const int extra = (blockIdx.x < REM && wv == (blockIdx.x & 7)) ? 1 : 0;
    const int niter = FULLR + extra;
    const int etile = FULLR * NWAVES + blockIdx.x;

#define TILE_OF(it) (((it) < FULLR) ? (gwave + (it) * NWAVES) : etile)
#define WFRAG(fid) (*(const f16x8*)&bfrag[(((fid) * 64) + lane) * 8])

    // ---- gather pipeline: data for it=0, idx for it=1 ----
    f16x8 pa0, pa1;
    float pd0 = 0.f, pd1 = 0.f, pd2 = 0.f;
    int xiB;
    {
        const int r0 = TILE_OF(0) * 16 + n0;
        const int x0 = x_idx[r0];
        const _Float16* xp = x16 + (long)x0 * 64 + q * 8;
        pa0 = *(const f16x8*)(xp);
        pa1 = *(const f16x8*)(xp + 32);
        if (q == 0) {
            const int yi = r0 >> 3;
            pd0 = pos_x[x0 * 3 + 0] - pos_y[yi * 3 + 0];
            pd1 = pos_x[x0 * 3 + 1] - pos_y[yi * 3 + 1];
            pd2 = pos_x[x0 * 3 + 2] - pos_y[yi * 3 + 2];
        }
        const int it1 = (1 < niter) ? 1 : niter - 1;
        xiB = x_idx[TILE_OF(it1) * 16 + n0];
    }

    for (int it = 0; it < niter; ++it) {
        const int tile = TILE_OF(it);

        // ---- consume prefetched B-frags ----
        f16x8 hn[3];
        hn[0] = pa0;
        hn[1] = pa1;
        {
            f16x8 z = {};
            hn[2] = z;
            if (q == 0) {
                hn[2][0] = (_Float16)pd0;
                hn[2][1] = (_Float16)pd1;
                hn[2][2] = (_Float16)pd2;
                hn[2][3] = (_Float16)1.0f;      // bias hook k=67 (b0a)
            }
        }

        // ---- prefetch: data for it+1 (via xiB), idx for it+2 ----
        {
            const int itn  = (it + 1 < niter) ? it + 1 : niter - 1;
            const int ntile = TILE_OF(itn);
            const _Float16* xp = x16 + (long)xiB * 64 + q * 8;
            pa0 = *(const f16x8*)(xp);
            pa1 = *(const f16x8*)(xp + 32);
            if (q == 0) {
                const int nyi = (ntile * 16 + n0) >> 3;
                pd0 = pos_x[xiB * 3 + 0] - pos_y[nyi * 3 + 0];
                pd1 = pos_x[xiB * 3 + 1] - pos_y[nyi * 3 + 1];
                pd2 = pos_x[xiB * 3 + 2] - pos_y[nyi * 3 + 2];
            }
            const int itn2 = (it + 2 < niter) ? it + 2 : niter - 1;
            xiB = x_idx[TILE_OF(itn2) * 16 + n0];
        }

        // ---- mm3 first (raw h): A2 = b1a + (h @ Wsa)^T ----
        f32x4 A2[4];
#pragma unroll
        for (int t = 0; t < 4; ++t)
            A2[t] = *(const f32x4*)&bias_lds[0 * 64 + t * 16 + q * 4];
#pragma unroll
        for (int s = 0; s < 3; ++s)
#pragma unroll
            for (int t = 0; t < 4; ++t)
                A2[t] = __builtin_amdgcn_mfma_f32_16x16x32_f16(WFRAG(12 + s * 4 + t), hn[s], A2[t], 0, 0, 0);

        // ---- relu h in place (pad 1.0 survives); mm1: A1 = net^T (+b0a via k67) ----
#pragma unroll
        for (int s = 0; s < 3; ++s)
#pragma unroll
            for (int j = 0; j < 8; ++j) {
                _Float16 v = hn[s][j];
                hn[s][j] = v > (_Float16)0 ? v : (_Float16)0;
            }
        f32x4 A1[4];
#pragma unroll
        for (int t = 0; t < 4; ++t) A1[t] = (f32x4){0.f, 0.f, 0.f, 0.f};
#pragma unroll
        for (int s = 0; s < 3; ++s)
#pragma unroll
            for (int t = 0; t < 4; ++t)
                A1[t] = __builtin_amdgcn_mfma_f32_16x16x32_f16(WFRAG(s * 4 + t), hn[s], A1[t], 0, 0, 0);

        // ---- mm2: A2 += (relu(net) @ W1a)^T   (B = repacked A1, no LDS) ----
        f16x8 bf[2];
        pack_relu(A1, bf);
#pragma unroll
        for (int t = 0; t < 4; ++t) {
            A2[t] = __builtin_amdgcn_mfma_f32_16x16x32_f16(WFRAG(24 + t), bf[0], A2[t], 0, 0, 0);
            A2[t] = __builtin_amdgcn_mfma_f32_16x16x32_f16(WFRAG(28 + t), bf[1], A2[t], 0, 0, 0);
        }

        // ---- mm4: A3 = b0b + (relu(h2) @ W0b)^T ----
        pack_relu(A2, bf);
        f32x4 A3[4];
#pragma unroll
        for (int t = 0; t < 4; ++t)
            A3[t] = *(const f32x4*)&bias_lds[1 * 64 + t * 16 + q * 4];
#pragma unroll
        for (int t = 0; t < 4; ++t) {
            A3[t] = __builtin_amdgcn_mfma_f32_16x16x32_f16(WFRAG(32 + t), bf[0], A3[t], 0, 0, 0);
            A3[t] = __builtin_amdgcn_mfma_f32_16x16x32_f16(WFRAG(36 + t), bf[1], A3[t], 0, 0, 0);
        }

        // ---- mm5: A2 += b1b + (relu(net2) @ W1b)^T  -> h3^T ----
        pack_relu(A3, bf);
#pragma unroll
        for (int t = 0; t < 4; ++t) {
            const f32x4 bv = *(const f32x4*)&bias_lds[2 * 64 + t * 16 + q * 4];
#pragma unroll
            for (int r = 0; r < 4; ++r) A2[t][r] += bv[r];
        }
#pragma unroll
        for (int t = 0; t < 4; ++t) {
            A2[t] = __builtin_amdgcn_mfma_f32_16x16x32_f16(WFRAG(40 + t), bf[0], A2[t], 0, 0, 0);
            A2[t] = __builtin_amdgcn_mfma_f32_16x16x32_f16(WFRAG(44 + t), bf[1], A2[t], 0, 0, 0);
        }

        // ---- epilogue: pack h3 to f16, shuffle-max over dr (lane bits 0..2) ----
        f16x2 pk[8];
#pragma unroll
        for (int t = 0; t < 4; ++t) {
            fp16x2_n c0 = __builtin_amdgcn_cvt_pkrtz(A2[t][0], A2[t][1]);
            fp16x2_n c1 = __builtin_amdgcn_cvt_pkrtz(A2[t][2], A2[t][3]);
            pk[2 * t]     = *(f16x2*)&c0;
            pk[2 * t + 1] = *(f16x2*)&c1;
        }
#pragma unroll
        for (int m = 1; m <= 4; m <<= 1) {
#pragma unroll
            for (int d = 0; d < 8; ++d) {
                int iv = *(int*)&pk[d];
                int ov = __shfl_xor(iv, m, 64);
                f16x2 o = *(f16x2*)&ov;
                pk[d][0] = pk[d][0] > o[0] ? pk[d][0] : o[0];
                pk[d][1] = pk[d][1] > o[1] ? pk[d][1] : o[1];
            }
        }
        if ((n0 & 7) == 0) {
            const int y = tile * 2 + (n0 >> 3);
            float* op = out + (long)y * 64;
#pragma unroll
            for (int t = 0; t < 4; ++t) {
                float4 f = {(float)pk[2 * t][0], (float)pk[2 * t][1],
                            (float)pk[2 * t + 1][0], (float)pk[2 * t + 1][1]};
                *(float4*)(op + t * 16 + q * 4) = f;
            }
        }
    }
#undef WFRAG
#undef TILE_OF
}

extern "C" void kernel_launch(void* const* d_in, const int* in_sizes, int n_in,
                              void* d_out, int out_size, void* d_ws, size_t ws_size,
                              hipStream_t stream) {
    (void)in_sizes; (void)n_in; (void)ws_size; (void)out_size;
    _Float16* x16 = (_Float16*)d_ws;

    prep_x<<<(NX * 16 + 255) / 256, 256, 0, stream>>>((const float*)d_in[0], x16);

    pointnet_fused<<<GRID, BLOCK, 0, stream>>>(
        x16,
        (const float*)d_in[1],   // pos_x
        (const float*)d_in[2],   // pos_y
        (const int*)  d_in[3],   // x_idx
        (const float*)d_in[5],  (const float*)d_in[6],   // W0a, b0a
        (const float*)d_in[7],  (const float*)d_in[8],   // W1a, b1a
        (const float*)d_in[9],                            // Wsa
        (const float*)d_in[10], (const float*)d_in[11],  // W0b, b0b
        (const float*)d_in[12], (const float*)d_in[13],  // W1b, b1b
        (float*)d_out);
}

// Round 13
// 487.349 us; speedup vs baseline: 1.0097x; 1.0097x over previous
//
#include <hip/hip_runtime.h>

// PointNetKnnInterpolator on MI355X (gfx950).
// h = [x[x_idx], pos_x[x_idx]-pos_y[y_idx]]  (400000 x 67)
// net = relu(h)@W0a+b0a ; dx = relu(net)@W1a+b1a ; h2 = h@Wsa + dx
// net2 = relu(h2)@W0b+b0b ; h3 = h2 + relu(net2)@W1b+b1b
// out[y] = max over 8 consecutive rows of h3.
//
// R13 = R12 with the scratch bug fixed: R12's epilogue did `*(int*)&pk[d]`
// (address-taken register array -> demoted to scratch -> 1.16 GB of HBM
// traffic, 417 us). Replaced with __builtin_bit_cast (no address, SROA keeps
// pk in VGPRs). Scheme (R10/R11): transposed MLP actT = WT@actT, weights=A
// from LDS (PHI-permuted K so accumulators re-feed as B-frags, 12 VALU, no
// LDS transposes); biases via accumulator init from 768B LDS table + k67
// hook; epilogue segment-max = 3 shfl_xor on f16-packed accs (dr = lane bits
// 0..3); LDS 48.8 KB -> 3 blocks/CU = 24 waves/CU; depth-2 gather prefetch;
// remainder tiles as 5th round spread 1-wave-per-block over blocks 0..423.

typedef _Float16 f16x8 __attribute__((ext_vector_type(8)));
typedef _Float16 f16x4 __attribute__((ext_vector_type(4)));
typedef _Float16 f16x2 __attribute__((ext_vector_type(2)));
typedef __fp16   fp16x2_n __attribute__((ext_vector_type(2)));  // builtin native
typedef float    f32x4 __attribute__((ext_vector_type(4)));

constexpr int NX     = 20000;
constexpr int NROWS  = 50000 * 8;    // NY * K
constexpr int NTILES = NROWS / 16;   // 25000
constexpr int NFRAG  = 48;           // g0:W0a 12, g1:Wsa 12, g2:W1a 8, g3:W0b 8, g4:W1b 8
constexpr int BW     = 8;            // waves per block
constexpr int BLOCK  = 64 * BW;      // 512
constexpr int GRID   = 768;          // 3 blocks/CU resident
constexpr int NWAVES = GRID * BW;    // 6144
constexpr int FULLR  = NTILES / NWAVES;        // 4 full rounds
constexpr int REM    = NTILES - FULLR * NWAVES; // 424 remainder tiles

__global__ void prep_x(const float* __restrict__ x, _Float16* __restrict__ x16) {
    const int i = blockIdx.x * blockDim.x + threadIdx.x;   // one float4 each
    if (i < NX * 16) {
        float4 v = ((const float4*)x)[i];
        f16x4 o = {(_Float16)v.x, (_Float16)v.y, (_Float16)v.z, (_Float16)v.w};
        *(f16x4*)(x16 + (size_t)i * 4) = o;
    }
}

// relu + repack accumulator (C-layout) into the two K=64 B-fragments.
// frag s element j <-> acc[t=2s+(j>>2)][r=j&3]  (matches PHI weight layout)
static __device__ __forceinline__ void pack_relu(const f32x4* A, f16x8* bf) {
#pragma unroll
    for (int s = 0; s < 2; ++s) {
        f16x8 r;
#pragma unroll
        for (int e = 0; e < 8; ++e) {
            float v = A[2 * s + (e >> 2)][e & 3];
            r[e] = (_Float16)(v > 0.0f ? v : 0.0f);
        }
        bf[s] = r;
    }
}

__global__ __launch_bounds__(BLOCK, 6)
void pointnet_fused(const _Float16* __restrict__ x16,
                    const float* __restrict__ pos_x,
                    const float* __restrict__ pos_y,
                    const int*   __restrict__ x_idx,
                    const float* __restrict__ W0a, const float* __restrict__ b0a,
                    const float* __restrict__ W1a, const float* __restrict__ b1a,
                    const float* __restrict__ Wsa,
                    const float* __restrict__ W0b, const float* __restrict__ b0b,
                    const float* __restrict__ W1b, const float* __restrict__ b1b,
                    float* __restrict__ out)
{
    __shared__ __align__(16) _Float16 bfrag[NFRAG * 64 * 8];   // 48 KiB
    __shared__ __align__(16) float bias_lds[3 * 64];           // 768 B: b1a,b0b,b1b

    const int tid = threadIdx.x;

    // ---- fill weight fragments (A operands, transposed; PHI-permuted K) ----
    // g0=W0a(identity K96, +b0a@k67) g1=Wsa(identity K96) g2=W1a g3=W0b g4=W1b (PHI K64)
    for (int p = tid; p < NFRAG * 64; p += BLOCK) {
        const int f = p >> 6, l = p & 63;
        const int q = l >> 4, n0 = l & 15;
        int grp, fl;
        if (f < 12)      { grp = 0; fl = f; }
        else if (f < 24) { grp = 1; fl = f - 12; }
        else if (f < 32) { grp = 2; fl = f - 24; }
        else if (f < 40) { grp = 3; fl = f - 32; }
        else             { grp = 4; fl = f - 40; }
        const int s = fl >> 2, t = fl & 3;
        const int col = t * 16 + n0;
        f16x8 v;
#pragma unroll
        for (int j = 0; j < 8; ++j) {
            const int k = 32 * s + 8 * q + j;
            float val = 0.0f;
            if (grp == 0)      val = (k < 67) ? W0a[k * 64 + col] : (k == 67 ? b0a[col] : 0.0f);
            else if (grp == 1) val = (k < 67) ? Wsa[k * 64 + col] : 0.0f;
            else {
                const float* W = (grp == 2) ? W1a : (grp == 3) ? W0b : W1b;
                const int row = 32 * s + 16 * (j >> 2) + 4 * q + (j & 3);  // PHI(k)
                val = W[row * 64 + col];
            }
            v[j] = (_Float16)val;
        }
        *(f16x8*)&bfrag[p * 8] = v;
    }
    if (tid < 192) {
        const int L = tid >> 6, i = tid & 63;
        const float* b = (L == 0) ? b1a : (L == 1) ? b0b : b1b;
        bias_lds[tid] = b[i];
    }
    __syncthreads();

    const int lane = tid & 63;
    const int wv   = tid >> 6;
    const int n0   = lane & 15;   // B col = data row (dr); A row m = out-feat%16
    const int q    = lane >> 4;

    const int gwave = blockIdx.x * BW + wv;
    const int extra = (blockIdx.x < REM && wv == (blockIdx.x & 7)) ? 1 : 0;
    const int niter = FULLR + extra;
    const int etile = FULLR * NWAVES + blockIdx.x;

#define TILE_OF(it) (((it) < FULLR) ? (gwave + (it) * NWAVES) : etile)
#define WFRAG(fid) (*(const f16x8*)&bfrag[(((fid) * 64) + lane) * 8])

    // ---- gather pipeline: data for it=0, idx for it=1 ----
    f16x8 pa0, pa1;
    float pd0 = 0.f, pd1 = 0.f, pd2 = 0.f;
    int xiB;
    {
        const int r0 = TILE_OF(0) * 16 + n0;
        const int x0 = x_idx[r0];
        const _Float16* xp = x16 + (long)x0 * 64 + q * 8;
        pa0 = *(const f16x8*)(xp);
        pa1 = *(const f16x8*)(xp + 32);
        if (q == 0) {
            const int yi = r0 >> 3;
            pd0 = pos_x[x0 * 3 + 0] - pos_y[yi * 3 + 0];
            pd1 = pos_x[x0 * 3 + 1] - pos_y[yi * 3 + 1];
            pd2 = pos_x[x0 * 3 + 2] - pos_y[yi * 3 + 2];
        }
        const int it1 = (1 < niter) ? 1 : niter - 1;
        xiB = x_idx[TILE_OF(it1) * 16 + n0];
    }

    for (int it = 0; it < niter; ++it) {
        const int tile = TILE_OF(it);

        // ---- consume prefetched B-frags ----
        f16x8 hn[3];
        hn[0] = pa0;
        hn[1] = pa1;
        {
            f16x8 z = {};
            hn[2] = z;
            if (q == 0) {
                hn[2][0] = (_Float16)pd0;
                hn[2][1] = (_Float16)pd1;
                hn[2][2] = (_Float16)pd2;
                hn[2][3] = (_Float16)1.0f;      // bias hook k=67 (b0a)
            }
        }

        // ---- prefetch: data for it+1 (via xiB), idx for it+2 ----
        {
            const int itn  = (it + 1 < niter) ? it + 1 : niter - 1;
            const int ntile = TILE_OF(itn);
            const _Float16* xp = x16 + (long)xiB * 64 + q * 8;
            pa0 = *(const f16x8*)(xp);
            pa1 = *(const f16x8*)(xp + 32);
            if (q == 0) {
                const int nyi = (ntile * 16 + n0) >> 3;
                pd0 = pos_x[xiB * 3 + 0] - pos_y[nyi * 3 + 0];
                pd1 = pos_x[xiB * 3 + 1] - pos_y[nyi * 3 + 1];
                pd2 = pos_x[xiB * 3 + 2] - pos_y[nyi * 3 + 2];
            }
            const int itn2 = (it + 2 < niter) ? it + 2 : niter - 1;
            xiB = x_idx[TILE_OF(itn2) * 16 + n0];
        }

        // ---- mm3 first (raw h): A2 = b1a + (h @ Wsa)^T ----
        f32x4 A2[4];
#pragma unroll
        for (int t = 0; t < 4; ++t)
            A2[t] = *(const f32x4*)&bias_lds[0 * 64 + t * 16 + q * 4];
#pragma unroll
        for (int s = 0; s < 3; ++s)
#pragma unroll
            for (int t = 0; t < 4; ++t)
                A2[t] = __builtin_amdgcn_mfma_f32_16x16x32_f16(WFRAG(12 + s * 4 + t), hn[s], A2[t], 0, 0, 0);

        // ---- relu h in place (pad 1.0 survives); mm1: A1 = net^T (+b0a via k67) ----
#pragma unroll
        for (int s = 0; s < 3; ++s)
#pragma unroll
            for (int j = 0; j < 8; ++j) {
                _Float16 v = hn[s][j];
                hn[s][j] = v > (_Float16)0 ? v : (_Float16)0;
            }
        f32x4 A1[4];
#pragma unroll
        for (int t = 0; t < 4; ++t) A1[t] = (f32x4){0.f, 0.f, 0.f, 0.f};
#pragma unroll
        for (int s = 0; s < 3; ++s)
#pragma unroll
            for (int t = 0; t < 4; ++t)
                A1[t] = __builtin_amdgcn_mfma_f32_16x16x32_f16(WFRAG(s * 4 + t), hn[s], A1[t], 0, 0, 0);

        // ---- mm2: A2 += (relu(net) @ W1a)^T   (B = repacked A1, no LDS) ----
        f16x8 bf[2];
        pack_relu(A1, bf);
#pragma unroll
        for (int t = 0; t < 4; ++t) {
            A2[t] = __builtin_amdgcn_mfma_f32_16x16x32_f16(WFRAG(24 + t), bf[0], A2[t], 0, 0, 0);
            A2[t] = __builtin_amdgcn_mfma_f32_16x16x32_f16(WFRAG(28 + t), bf[1], A2[t], 0, 0, 0);
        }

        // ---- mm4: A3 = b0b + (relu(h2) @ W0b)^T ----
        pack_relu(A2, bf);
        f32x4 A3[4];
#pragma unroll
        for (int t = 0; t < 4; ++t)
            A3[t] = *(const f32x4*)&bias_lds[1 * 64 + t * 16 + q * 4];
#pragma unroll
        for (int t = 0; t < 4; ++t) {
            A3[t] = __builtin_amdgcn_mfma_f32_16x16x32_f16(WFRAG(32 + t), bf[0], A3[t], 0, 0, 0);
            A3[t] = __builtin_amdgcn_mfma_f32_16x16x32_f16(WFRAG(36 + t), bf[1], A3[t], 0, 0, 0);
        }

        // ---- mm5: A2 += b1b + (relu(net2) @ W1b)^T  -> h3^T ----
        pack_relu(A3, bf);
#pragma unroll
        for (int t = 0; t < 4; ++t) {
            const f32x4 bv = *(const f32x4*)&bias_lds[2 * 64 + t * 16 + q * 4];
#pragma unroll
            for (int r = 0; r < 4; ++r) A2[t][r] += bv[r];
        }
#pragma unroll
        for (int t = 0; t < 4; ++t) {
            A2[t] = __builtin_amdgcn_mfma_f32_16x16x32_f16(WFRAG(40 + t), bf[0], A2[t], 0, 0, 0);
            A2[t] = __builtin_amdgcn_mfma_f32_16x16x32_f16(WFRAG(44 + t), bf[1], A2[t], 0, 0, 0);
        }

        // ---- epilogue: pack h3 to f16, shuffle-max over dr (lane bits 0..2) ----
        // NOTE: bit_cast only — taking &pk[d] demotes pk to scratch (R12: 1.16 GB HBM).
        f16x2 pk[8];
#pragma unroll
        for (int t = 0; t < 4; ++t) {
            fp16x2_n c0 = __builtin_amdgcn_cvt_pkrtz(A2[t][0], A2[t][1]);
            fp16x2_n c1 = __builtin_amdgcn_cvt_pkrtz(A2[t][2], A2[t][3]);
            pk[2 * t]     = __builtin_bit_cast(f16x2, c0);
            pk[2 * t + 1] = __builtin_bit_cast(f16x2, c1);
        }
#pragma unroll
        for (int m = 1; m <= 4; m <<= 1) {
#pragma unroll
            for (int d = 0; d < 8; ++d) {
                const int iv = __builtin_bit_cast(int, pk[d]);
                const int ov = __shfl_xor(iv, m, 64);
                const f16x2 o = __builtin_bit_cast(f16x2, ov);
                pk[d][0] = pk[d][0] > o[0] ? pk[d][0] : o[0];
                pk[d][1] = pk[d][1] > o[1] ? pk[d][1] : o[1];
            }
        }
        if ((n0 & 7) == 0) {
            const int y = tile * 2 + (n0 >> 3);
            float* op = out + (long)y * 64;
#pragma unroll
            for (int t = 0; t < 4; ++t) {
                float4 f = {(float)pk[2 * t][0], (float)pk[2 * t][1],
                            (float)pk[2 * t + 1][0], (float)pk[2 * t + 1][1]};
                *(float4*)(op + t * 16 + q * 4) = f;
            }
        }
    }
#undef WFRAG
#undef TILE_OF
}

extern "C" void kernel_launch(void* const* d_in, const int* in_sizes, int n_in,
                              void* d_out, int out_size, void* d_ws, size_t ws_size,
                              hipStream_t stream) {
    (void)in_sizes; (void)n_in; (void)ws_size; (void)out_size;
    _Float16* x16 = (_Float16*)d_ws;

    prep_x<<<(NX * 16 + 255) / 256, 256, 0, stream>>>((const float*)d_in[0], x16);

    pointnet_fused<<<GRID, BLOCK, 0, stream>>>(
        x16,
        (const float*)d_in[1],   // pos_x
        (const float*)d_in[2],   // pos_y
        (const int*)  d_in[3],   // x_idx
        (const float*)d_in[5],  (const float*)d_in[6],   // W0a, b0a
        (const float*)d_in[7],  (const float*)d_in[8],   // W1a, b1a
        (const float*)d_in[9],                            // Wsa
        (const float*)d_in[10], (const float*)d_in[11],  // W0b, b0b
        (const float*)d_in[12], (const float*)d_in[13],  // W1b, b1b
        (float*)d_out);
}

// Round 14
// 369.363 us; speedup vs baseline: 1.3323x; 1.3194x over previous
//
#include <hip/hip_runtime.h>

// PointNetKnnInterpolator on MI355X (gfx950).
// h = [x[x_idx], pos_x[x_idx]-pos_y[y_idx]]  (400000 x 67)
// net = relu(h)@W0a+b0a ; dx = relu(net)@W1a+b1a ; h2 = h@Wsa + dx
// net2 = relu(h2)@W0b+b0b ; h3 = h2 + relu(net2)@W1b+b1b
// out[y] = max over 8 consecutive rows of h3.
//
// R14 = R13 with __launch_bounds__(512,4). R12/R13's 417us was REGISTER-BUDGET
// spill: (512,6) caps VGPR at ~85; the prefetch+remainder additions pushed the
// working set past it -> allocator demoted arrays to scratch (1.16 GB HBM,
// VGPR_Count 40 = demotion fingerprint; same class as R4). R9 proved 24 vs 16
// waves/CU is neutral here, so the tight bound bought nothing. Cap back to 128
// (R10's proven-clean budget).
// Scheme (R10/R11): transposed MLP actT = WT@actT, weights=A from LDS
// (PHI-permuted K so accumulators re-feed as B-frags, 12 VALU, no LDS
// transposes); biases via accumulator init from 768B LDS table + k67 hook;
// epilogue segment-max = 3 shfl_xor on f16-packed accs (dr = lane bits 0..3);
// LDS 48.8 KB; depth-2 gather prefetch; remainder tiles as 5th round spread
// 1-wave-per-block over blocks 0..423.

typedef _Float16 f16x8 __attribute__((ext_vector_type(8)));
typedef _Float16 f16x4 __attribute__((ext_vector_type(4)));
typedef _Float16 f16x2 __attribute__((ext_vector_type(2)));
typedef __fp16   fp16x2_n __attribute__((ext_vector_type(2)));  // builtin native
typedef float    f32x4 __attribute__((ext_vector_type(4)));

constexpr int NX     = 20000;
constexpr int NROWS  = 50000 * 8;    // NY * K
constexpr int NTILES = NROWS / 16;   // 25000
constexpr int NFRAG  = 48;           // g0:W0a 12, g1:Wsa 12, g2:W1a 8, g3:W0b 8, g4:W1b 8
constexpr int BW     = 8;            // waves per block
constexpr int BLOCK  = 64 * BW;      // 512
constexpr int GRID   = 768;
constexpr int NWAVES = GRID * BW;    // 6144
constexpr int FULLR  = NTILES / NWAVES;        // 4 full rounds
constexpr int REM    = NTILES - FULLR * NWAVES; // 424 remainder tiles

__global__ void prep_x(const float* __restrict__ x, _Float16* __restrict__ x16) {
    const int i = blockIdx.x * blockDim.x + threadIdx.x;   // one float4 each
    if (i < NX * 16) {
        float4 v = ((const float4*)x)[i];
        f16x4 o = {(_Float16)v.x, (_Float16)v.y, (_Float16)v.z, (_Float16)v.w};
        *(f16x4*)(x16 + (size_t)i * 4) = o;
    }
}

// relu + repack accumulator (C-layout) into the two K=64 B-fragments.
// frag s element j <-> acc[t=2s+(j>>2)][r=j&3]  (matches PHI weight layout)
static __device__ __forceinline__ void pack_relu(const f32x4* A, f16x8* bf) {
#pragma unroll
    for (int s = 0; s < 2; ++s) {
        f16x8 r;
#pragma unroll
        for (int e = 0; e < 8; ++e) {
            float v = A[2 * s + (e >> 2)][e & 3];
            r[e] = (_Float16)(v > 0.0f ? v : 0.0f);
        }
        bf[s] = r;
    }
}

__global__ __launch_bounds__(BLOCK, 4)
void pointnet_fused(const _Float16* __restrict__ x16,
                    const float* __restrict__ pos_x,
                    const float* __restrict__ pos_y,
                    const int*   __restrict__ x_idx,
                    const float* __restrict__ W0a, const float* __restrict__ b0a,
                    const float* __restrict__ W1a, const float* __restrict__ b1a,
                    const float* __restrict__ Wsa,
                    const float* __restrict__ W0b, const float* __restrict__ b0b,
                    const float* __restrict__ W1b, const float* __restrict__ b1b,
                    float* __restrict__ out)
{
    __shared__ __align__(16) _Float16 bfrag[NFRAG * 64 * 8];   // 48 KiB
    __shared__ __align__(16) float bias_lds[3 * 64];           // 768 B: b1a,b0b,b1b

    const int tid = threadIdx.x;

    // ---- fill weight fragments (A operands, transposed; PHI-permuted K) ----
    // g0=W0a(identity K96, +b0a@k67) g1=Wsa(identity K96) g2=W1a g3=W0b g4=W1b (PHI K64)
    for (int p = tid; p < NFRAG * 64; p += BLOCK) {
        const int f = p >> 6, l = p & 63;
        const int q = l >> 4, n0 = l & 15;
        int grp, fl;
        if (f < 12)      { grp = 0; fl = f; }
        else if (f < 24) { grp = 1; fl = f - 12; }
        else if (f < 32) { grp = 2; fl = f - 24; }
        else if (f < 40) { grp = 3; fl = f - 32; }
        else             { grp = 4; fl = f - 40; }
        const int s = fl >> 2, t = fl & 3;
        const int col = t * 16 + n0;
        f16x8 v;
#pragma unroll
        for (int j = 0; j < 8; ++j) {
            const int k = 32 * s + 8 * q + j;
            float val = 0.0f;
            if (grp == 0)      val = (k < 67) ? W0a[k * 64 + col] : (k == 67 ? b0a[col] : 0.0f);
            else if (grp == 1) val = (k < 67) ? Wsa[k * 64 + col] : 0.0f;
            else {
                const float* W = (grp == 2) ? W1a : (grp == 3) ? W0b : W1b;
                const int row = 32 * s + 16 * (j >> 2) + 4 * q + (j & 3);  // PHI(k)
                val = W[row * 64 + col];
            }
            v[j] = (_Float16)val;
        }
        *(f16x8*)&bfrag[p * 8] = v;
    }
    if (tid < 192) {
        const int L = tid >> 6, i = tid & 63;
        const float* b = (L == 0) ? b1a : (L == 1) ? b0b : b1b;
        bias_lds[tid] = b[i];
    }
    __syncthreads();

    const int lane = tid & 63;
    const int wv   = tid >> 6;
    const int n0   = lane & 15;   // B col = data row (dr); A row m = out-feat%16
    const int q    = lane >> 4;

    const int gwave = blockIdx.x * BW + wv;
    const int extra = (blockIdx.x < REM && wv == (blockIdx.x & 7)) ? 1 : 0;
    const int niter = FULLR + extra;
    const int etile = FULLR * NWAVES + blockIdx.x;

#define TILE_OF(it) (((it) < FULLR) ? (gwave + (it) * NWAVES) : etile)
#define WFRAG(fid) (*(const f16x8*)&bfrag[(((fid) * 64) + lane) * 8])

    // ---- gather pipeline: data for it=0, idx for it=1 ----
    f16x8 pa0, pa1;
    float pd0 = 0.f, pd1 = 0.f, pd2 = 0.f;
    int xiB;
    {
        const int r0 = TILE_OF(0) * 16 + n0;
        const int x0 = x_idx[r0];
        const _Float16* xp = x16 + (long)x0 * 64 + q * 8;
        pa0 = *(const f16x8*)(xp);
        pa1 = *(const f16x8*)(xp + 32);
        if (q == 0) {
            const int yi = r0 >> 3;
            pd0 = pos_x[x0 * 3 + 0] - pos_y[yi * 3 + 0];
            pd1 = pos_x[x0 * 3 + 1] - pos_y[yi * 3 + 1];
            pd2 = pos_x[x0 * 3 + 2] - pos_y[yi * 3 + 2];
        }
        const int it1 = (1 < niter) ? 1 : niter - 1;
        xiB = x_idx[TILE_OF(it1) * 16 + n0];
    }

    for (int it = 0; it < niter; ++it) {
        const int tile = TILE_OF(it);

        // ---- consume prefetched B-frags ----
        f16x8 hn[3];
        hn[0] = pa0;
        hn[1] = pa1;
        {
            f16x8 z = {};
            hn[2] = z;
            if (q == 0) {
                hn[2][0] = (_Float16)pd0;
                hn[2][1] = (_Float16)pd1;
                hn[2][2] = (_Float16)pd2;
                hn[2][3] = (_Float16)1.0f;      // bias hook k=67 (b0a)
            }
        }

        // ---- prefetch: data for it+1 (via xiB), idx for it+2 ----
        {
            const int itn  = (it + 1 < niter) ? it + 1 : niter - 1;
            const int ntile = TILE_OF(itn);
            const _Float16* xp = x16 + (long)xiB * 64 + q * 8;
            pa0 = *(const f16x8*)(xp);
            pa1 = *(const f16x8*)(xp + 32);
            if (q == 0) {
                const int nyi = (ntile * 16 + n0) >> 3;
                pd0 = pos_x[xiB * 3 + 0] - pos_y[nyi * 3 + 0];
                pd1 = pos_x[xiB * 3 + 1] - pos_y[nyi * 3 + 1];
                pd2 = pos_x[xiB * 3 + 2] - pos_y[nyi * 3 + 2];
            }
            const int itn2 = (it + 2 < niter) ? it + 2 : niter - 1;
            xiB = x_idx[TILE_OF(itn2) * 16 + n0];
        }

        // ---- mm3 first (raw h): A2 = b1a + (h @ Wsa)^T ----
        f32x4 A2[4];
#pragma unroll
        for (int t = 0; t < 4; ++t)
            A2[t] = *(const f32x4*)&bias_lds[0 * 64 + t * 16 + q * 4];
#pragma unroll
        for (int s = 0; s < 3; ++s)
#pragma unroll
            for (int t = 0; t < 4; ++t)
                A2[t] = __builtin_amdgcn_mfma_f32_16x16x32_f16(WFRAG(12 + s * 4 + t), hn[s], A2[t], 0, 0, 0);

        // ---- relu h in place (pad 1.0 survives); mm1: A1 = net^T (+b0a via k67) ----
#pragma unroll
        for (int s = 0; s < 3; ++s)
#pragma unroll
            for (int j = 0; j < 8; ++j) {
                _Float16 v = hn[s][j];
                hn[s][j] = v > (_Float16)0 ? v : (_Float16)0;
            }
        f32x4 A1[4];
#pragma unroll
        for (int t = 0; t < 4; ++t) A1[t] = (f32x4){0.f, 0.f, 0.f, 0.f};
#pragma unroll
        for (int s = 0; s < 3; ++s)
#pragma unroll
            for (int t = 0; t < 4; ++t)
                A1[t] = __builtin_amdgcn_mfma_f32_16x16x32_f16(WFRAG(s * 4 + t), hn[s], A1[t], 0, 0, 0);

        // ---- mm2: A2 += (relu(net) @ W1a)^T   (B = repacked A1, no LDS) ----
        f16x8 bf[2];
        pack_relu(A1, bf);
#pragma unroll
        for (int t = 0; t < 4; ++t) {
            A2[t] = __builtin_amdgcn_mfma_f32_16x16x32_f16(WFRAG(24 + t), bf[0], A2[t], 0, 0, 0);
            A2[t] = __builtin_amdgcn_mfma_f32_16x16x32_f16(WFRAG(28 + t), bf[1], A2[t], 0, 0, 0);
        }

        // ---- mm4: A3 = b0b + (relu(h2) @ W0b)^T ----
        pack_relu(A2, bf);
        f32x4 A3[4];
#pragma unroll
        for (int t = 0; t < 4; ++t)
            A3[t] = *(const f32x4*)&bias_lds[1 * 64 + t * 16 + q * 4];
#pragma unroll
        for (int t = 0; t < 4; ++t) {
            A3[t] = __builtin_amdgcn_mfma_f32_16x16x32_f16(WFRAG(32 + t), bf[0], A3[t], 0, 0, 0);
            A3[t] = __builtin_amdgcn_mfma_f32_16x16x32_f16(WFRAG(36 + t), bf[1], A3[t], 0, 0, 0);
        }

        // ---- mm5: A2 += b1b + (relu(net2) @ W1b)^T  -> h3^T ----
        pack_relu(A3, bf);
#pragma unroll
        for (int t = 0; t < 4; ++t) {
            const f32x4 bv = *(const f32x4*)&bias_lds[2 * 64 + t * 16 + q * 4];
#pragma unroll
            for (int r = 0; r < 4; ++r) A2[t][r] += bv[r];
        }
#pragma unroll
        for (int t = 0; t < 4; ++t) {
            A2[t] = __builtin_amdgcn_mfma_f32_16x16x32_f16(WFRAG(40 + t), bf[0], A2[t], 0, 0, 0);
            A2[t] = __builtin_amdgcn_mfma_f32_16x16x32_f16(WFRAG(44 + t), bf[1], A2[t], 0, 0, 0);
        }

        // ---- epilogue: pack h3 to f16, shuffle-max over dr (lane bits 0..2) ----
        f16x2 pk[8];
#pragma unroll
        for (int t = 0; t < 4; ++t) {
            fp16x2_n c0 = __builtin_amdgcn_cvt_pkrtz(A2[t][0], A2[t][1]);
            fp16x2_n c1 = __builtin_amdgcn_cvt_pkrtz(A2[t][2], A2[t][3]);
            pk[2 * t]     = __builtin_bit_cast(f16x2, c0);
            pk[2 * t + 1] = __builtin_bit_cast(f16x2, c1);
        }
#pragma unroll
        for (int m = 1; m <= 4; m <<= 1) {
#pragma unroll
            for (int d = 0; d < 8; ++d) {
                const int iv = __builtin_bit_cast(int, pk[d]);
                const int ov = __shfl_xor(iv, m, 64);
                const f16x2 o = __builtin_bit_cast(f16x2, ov);
                pk[d][0] = pk[d][0] > o[0] ? pk[d][0] : o[0];
                pk[d][1] = pk[d][1] > o[1] ? pk[d][1] : o[1];
            }
        }
        if ((n0 & 7) == 0) {
            const int y = tile * 2 + (n0 >> 3);
            float* op = out + (long)y * 64;
#pragma unroll
            for (int t = 0; t < 4; ++t) {
                float4 f = {(float)pk[2 * t][0], (float)pk[2 * t][1],
                            (float)pk[2 * t + 1][0], (float)pk[2 * t + 1][1]};
                *(float4*)(op + t * 16 + q * 4) = f;
            }
        }
    }
#undef WFRAG
#undef TILE_OF
}

extern "C" void kernel_launch(void* const* d_in, const int* in_sizes, int n_in,
                              void* d_out, int out_size, void* d_ws, size_t ws_size,
                              hipStream_t stream) {
    (void)in_sizes; (void)n_in; (void)ws_size; (void)out_size;
    _Float16* x16 = (_Float16*)d_ws;

    prep_x<<<(NX * 16 + 255) / 256, 256, 0, stream>>>((const float*)d_in[0], x16);

    pointnet_fused<<<GRID, BLOCK, 0, stream>>>(
        x16,
        (const float*)d_in[1],   // pos_x
        (const float*)d_in[2],   // pos_y
        (const int*)  d_in[3],   // x_idx
        (const float*)d_in[5],  (const float*)d_in[6],   // W0a, b0a
        (const float*)d_in[7],  (const float*)d_in[8],   // W1a, b1a
        (const float*)d_in[9],                            // Wsa
        (const float*)d_in[10], (const float*)d_in[11],  // W0b, b0b
        (const float*)d_in[12], (const float*)d_in[13],  // W1b, b1b
        (float*)d_out);
}

// Round 15
// 124.022 us; speedup vs baseline: 3.9678x; 2.9782x over previous
//
#include <hip/hip_runtime.h>

// PointNetKnnInterpolator on MI355X (gfx950).
// h = [x[x_idx], pos_x[x_idx]-pos_y[y_idx]]  (400000 x 67)
// net = relu(h)@W0a+b0a ; dx = relu(net)@W1a+b1a ; h2 = h@Wsa + dx
// net2 = relu(h2)@W0b+b0b ; h3 = h2 + relu(net2)@W1b+b1b
// out[y] = max over 8 consecutive rows of h3.
//
// R15 = R10 (last PROVEN-clean structure: 47us, VGPR 52, no scratch) + two
// audited deltas. R11-R14's prefetch/shfl-epilogue/remainder combo caused
// unattributable scratch demotion (950MB HBM) — discarded wholesale.
//   delta 1: bias MFMAs -> LDS accumulator-init (NFRAG 60->48: -12 MFMA,
//            -12 ds_read_b128 per tile).
//   delta 2: TWO tiles per wave. In the transposed scheme the shared operand
//            is the weight A-frag = the dominant LDS stream (~500-700 cyc/tile
//            of ~1155) -> pairing halves it (48->24 KB/tile). Live-range
//            audit ~110 VGPRs peak; __launch_bounds__(512,3) caps ~168 (slack
//            against the R4/R12 spill trap). Occupancy stays LDS-bound at
//            2 blocks/CU (67 KB) = 16 waves/CU — R9 proved more is neutral.
// Epilogue and gather are R10's verbatim (union-shfl, inline gather, no
// prefetch). Remainder: 12500 = 3*4096 + 212 -> pair 12288+b as a 4th round
// on one wave of block b (b<212); <=4% CU imbalance, keeps locality.

typedef _Float16 f16x8 __attribute__((ext_vector_type(8)));
typedef _Float16 f16x4 __attribute__((ext_vector_type(4)));
typedef float    f32x4 __attribute__((ext_vector_type(4)));

constexpr int NX     = 20000;
constexpr int NROWS  = 50000 * 8;    // NY * K
constexpr int NPAIRS = NROWS / 32;   // 12500
constexpr int NFRAG  = 48;           // g0:W0a 12, g1:Wsa 12, g2:W1a 8, g3:W0b 8, g4:W1b 8
constexpr int BW     = 8;            // waves per block
constexpr int BLOCK  = 64 * BW;      // 512
constexpr int GRID   = 512;
constexpr int NWAVES = GRID * BW;    // 4096
constexpr int FULLR  = NPAIRS / NWAVES;          // 3
constexpr int REM    = NPAIRS - FULLR * NWAVES;  // 212
constexpr int TS2    = 72;           // epilogue buffer row stride in f16

__global__ void prep_x(const float* __restrict__ x, _Float16* __restrict__ x16) {
    const int i = blockIdx.x * blockDim.x + threadIdx.x;   // one float4 each
    if (i < NX * 16) {
        float4 v = ((const float4*)x)[i];
        f16x4 o = {(_Float16)v.x, (_Float16)v.y, (_Float16)v.z, (_Float16)v.w};
        *(f16x4*)(x16 + (size_t)i * 4) = o;
    }
}

// relu + repack accumulator (C-layout) into the two K=64 B-fragments.
// frag s element j <-> acc[t=2s+(j>>2)][r=j&3]  (matches PHI weight layout)
static __device__ __forceinline__ void pack_relu(const f32x4* A, f16x8* bf) {
#pragma unroll
    for (int s = 0; s < 2; ++s) {
        f16x8 r;
#pragma unroll
        for (int e = 0; e < 8; ++e) {
            float v = A[2 * s + (e >> 2)][e & 3];
            r[e] = (_Float16)(v > 0.0f ? v : 0.0f);
        }
        bf[s] = r;
    }
}

__global__ __launch_bounds__(BLOCK, 3)
void pointnet_fused(const _Float16* __restrict__ x16,
                    const float* __restrict__ pos_x,
                    const float* __restrict__ pos_y,
                    const int*   __restrict__ x_idx,
                    const float* __restrict__ W0a, const float* __restrict__ b0a,
                    const float* __restrict__ W1a, const float* __restrict__ b1a,
                    const float* __restrict__ Wsa,
                    const float* __restrict__ W0b, const float* __restrict__ b0b,
                    const float* __restrict__ W1b, const float* __restrict__ b1b,
                    float* __restrict__ out)
{
    __shared__ __align__(16) _Float16 bfrag[NFRAG * 64 * 8];   // 48 KiB
    __shared__ __align__(16) _Float16 ebuf[BW][16 * TS2];      // 18 KiB
    __shared__ __align__(16) float bias_lds[3 * 64];           // 768 B: b1a,b0b,b1b

    const int tid = threadIdx.x;

    // ---- fill weight fragments (A operands, transposed; PHI-permuted K) ----
    // g0=W0a(identity K96, +b0a@k67) g1=Wsa(identity K96) g2=W1a g3=W0b g4=W1b (PHI K64)
    for (int p = tid; p < NFRAG * 64; p += BLOCK) {
        const int f = p >> 6, l = p & 63;
        const int q = l >> 4, n0 = l & 15;
        int grp, fl;
        if (f < 12)      { grp = 0; fl = f; }
        else if (f < 24) { grp = 1; fl = f - 12; }
        else if (f < 32) { grp = 2; fl = f - 24; }
        else if (f < 40) { grp = 3; fl = f - 32; }
        else             { grp = 4; fl = f - 40; }
        const int s = fl >> 2, t = fl & 3;
        const int col = t * 16 + n0;
        f16x8 v;
#pragma unroll
        for (int j = 0; j < 8; ++j) {
            const int k = 32 * s + 8 * q + j;
            float val = 0.0f;
            if (grp == 0)      val = (k < 67) ? W0a[k * 64 + col] : (k == 67 ? b0a[col] : 0.0f);
            else if (grp == 1) val = (k < 67) ? Wsa[k * 64 + col] : 0.0f;
            else {
                const float* W = (grp == 2) ? W1a : (grp == 3) ? W0b : W1b;
                const int row = 32 * s + 16 * (j >> 2) + 4 * q + (j & 3);  // PHI(k)
                val = W[row * 64 + col];
            }
            v[j] = (_Float16)val;
        }
        *(f16x8*)&bfrag[p * 8] = v;
    }
    if (tid < 192) {
        const int L = tid >> 6, i = tid & 63;
        const float* b = (L == 0) ? b1a : (L == 1) ? b0b : b1b;
        bias_lds[tid] = b[i];
    }
    __syncthreads();

    const int lane = tid & 63;
    const int wv   = tid >> 6;
    const int n0   = lane & 15;   // B col = data row (dr); A row m = out-feat%16
    const int q    = lane >> 4;

    _Float16* eb = ebuf[wv];

    // epilogue lane roles (R10 verbatim)
    const int ey  = (lane >> 3) & 1;   // y within tile
    const int efg = lane & 7;          // feature group of 8
    const int esb = lane >> 4;         // sub: covers 2 drs

    const int gwave = blockIdx.x * BW + wv;
    const int extra = (blockIdx.x < REM && wv == (blockIdx.x & 7)) ? 1 : 0;
    const int niter = FULLR + extra;
    const int epair = FULLR * NWAVES + blockIdx.x;   // remainder pair id

#define WFRAG(fid) (*(const f16x8*)&bfrag[(((fid) * 64) + lane) * 8])

    for (int it = 0; it < niter; ++it) {
        const int pair = (it < FULLR) ? (gwave + it * NWAVES) : epair;

        // ---- gather h^T B-frags for both tiles (R10-style inline) ----
        f16x8 hn[2][3];
#pragma unroll
        for (int u = 0; u < 2; ++u) {
            const int row = pair * 32 + u * 16 + n0;
            const int xi  = x_idx[row];
            const _Float16* xp = x16 + (long)xi * 64 + q * 8;
            hn[u][0] = *(const f16x8*)(xp);
            hn[u][1] = *(const f16x8*)(xp + 32);
            f16x8 z = {};
            hn[u][2] = z;
            if (q == 0) {                      // k=64..66 diff, k=67 = 1.0 (b0a hook)
                const int yi = row >> 3;
#pragma unroll
                for (int j = 0; j < 3; ++j)
                    hn[u][2][j] = (_Float16)(pos_x[xi * 3 + j] - pos_y[yi * 3 + j]);
                hn[u][2][3] = (_Float16)1.0f;
            }
        }

        // ---- mm3 first (raw h): A2 = b1a + (h @ Wsa)^T  (weight frag shared) ----
        f32x4 A2[2][4];
#pragma unroll
        for (int t = 0; t < 4; ++t) {
            const f32x4 bv = *(const f32x4*)&bias_lds[0 * 64 + t * 16 + q * 4];
            A2[0][t] = bv;
            A2[1][t] = bv;
        }
#pragma unroll
        for (int s = 0; s < 3; ++s)
#pragma unroll
            for (int t = 0; t < 4; ++t) {
                const f16x8 w = WFRAG(12 + s * 4 + t);
                A2[0][t] = __builtin_amdgcn_mfma_f32_16x16x32_f16(w, hn[0][s], A2[0][t], 0, 0, 0);
                A2[1][t] = __builtin_amdgcn_mfma_f32_16x16x32_f16(w, hn[1][s], A2[1][t], 0, 0, 0);
            }

        // ---- relu h in place (pad 1.0 survives); mm1: A1 = net^T (+b0a via k67) ----
#pragma unroll
        for (int u = 0; u < 2; ++u)
#pragma unroll
            for (int s = 0; s < 3; ++s)
#pragma unroll
                for (int j = 0; j < 8; ++j) {
                    _Float16 v = hn[u][s][j];
                    hn[u][s][j] = v > (_Float16)0 ? v : (_Float16)0;
                }
        f32x4 A1[2][4];
#pragma unroll
        for (int u = 0; u < 2; ++u)
#pragma unroll
            for (int t = 0; t < 4; ++t) A1[u][t] = (f32x4){0.f, 0.f, 0.f, 0.f};
#pragma unroll
        for (int s = 0; s < 3; ++s)
#pragma unroll
            for (int t = 0; t < 4; ++t) {
                const f16x8 w = WFRAG(s * 4 + t);
                A1[0][t] = __builtin_amdgcn_mfma_f32_16x16x32_f16(w, hn[0][s], A1[0][t], 0, 0, 0);
                A1[1][t] = __builtin_amdgcn_mfma_f32_16x16x32_f16(w, hn[1][s], A1[1][t], 0, 0, 0);
            }

        // ---- mm2: A2 += (relu(net) @ W1a)^T   (B = repacked A1, no LDS) ----
        f16x8 bf[2][2];
        pack_relu(A1[0], bf[0]);
        pack_relu(A1[1], bf[1]);
#pragma unroll
        for (int s = 0; s < 2; ++s)
#pragma unroll
            for (int t = 0; t < 4; ++t) {
                const f16x8 w = WFRAG(24 + s * 4 + t);
                A2[0][t] = __builtin_amdgcn_mfma_f32_16x16x32_f16(w, bf[0][s], A2[0][t], 0, 0, 0);
                A2[1][t] = __builtin_amdgcn_mfma_f32_16x16x32_f16(w, bf[1][s], A2[1][t], 0, 0, 0);
            }

        // ---- mm4: A3 = b0b + (relu(h2) @ W0b)^T ----
        pack_relu(A2[0], bf[0]);
        pack_relu(A2[1], bf[1]);
        f32x4 A3[2][4];
#pragma unroll
        for (int t = 0; t < 4; ++t) {
            const f32x4 bv = *(const f32x4*)&bias_lds[1 * 64 + t * 16 + q * 4];
            A3[0][t] = bv;
            A3[1][t] = bv;
        }
#pragma unroll
        for (int s = 0; s < 2; ++s)
#pragma unroll
            for (int t = 0; t < 4; ++t) {
                const f16x8 w = WFRAG(32 + s * 4 + t);
                A3[0][t] = __builtin_amdgcn_mfma_f32_16x16x32_f16(w, bf[0][s], A3[0][t], 0, 0, 0);
                A3[1][t] = __builtin_amdgcn_mfma_f32_16x16x32_f16(w, bf[1][s], A3[1][t], 0, 0, 0);
            }

        // ---- mm5: A2 += b1b + (relu(net2) @ W1b)^T  -> h3^T ----
        pack_relu(A3[0], bf[0]);
        pack_relu(A3[1], bf[1]);
#pragma unroll
        for (int t = 0; t < 4; ++t) {
            const f32x4 bv = *(const f32x4*)&bias_lds[2 * 64 + t * 16 + q * 4];
#pragma unroll
            for (int r = 0; r < 4; ++r) {
                A2[0][t][r] += bv[r];
                A2[1][t][r] += bv[r];
            }
        }
#pragma unroll
        for (int s = 0; s < 2; ++s)
#pragma unroll
            for (int t = 0; t < 4; ++t) {
                const f16x8 w = WFRAG(40 + s * 4 + t);
                A2[0][t] = __builtin_amdgcn_mfma_f32_16x16x32_f16(w, bf[0][s], A2[0][t], 0, 0, 0);
                A2[1][t] = __builtin_amdgcn_mfma_f32_16x16x32_f16(w, bf[1][s], A2[1][t], 0, 0, 0);
            }

        // ---- epilogue per tile (R10 verbatim): ebuf round-trip + union shfl ----
#pragma unroll
        for (int u = 0; u < 2; ++u) {
            __threadfence_block();
#pragma unroll
            for (int t = 0; t < 4; ++t) {
                f16x4 w;
#pragma unroll
                for (int r = 0; r < 4; ++r) w[r] = (_Float16)A2[u][t][r];
                *(f16x4*)&eb[n0 * TS2 + t * 16 + q * 4] = w;   // feat = 16t+4q+r
            }
            __threadfence_block();

            const int dr0 = ey * 8 + esb * 2;
            f16x8 ra = *(const f16x8*)&eb[dr0 * TS2 + efg * 8];
            f16x8 rb = *(const f16x8*)&eb[(dr0 + 1) * TS2 + efg * 8];
#pragma unroll
            for (int e = 0; e < 8; ++e) ra[e] = ra[e] > rb[e] ? ra[e] : rb[e];
#pragma unroll
            for (int st = 0; st < 2; ++st) {
                union { f16x8 h; int i[4]; } uu, vv;
                uu.h = ra;
#pragma unroll
                for (int d = 0; d < 4; ++d) vv.i[d] = __shfl_xor(uu.i[d], st == 0 ? 16 : 32, 64);
#pragma unroll
                for (int e = 0; e < 8; ++e) ra[e] = ra[e] > vv.h[e] ? ra[e] : vv.h[e];
            }
            if (esb == 0) {
                float4 f0 = {(float)ra[0], (float)ra[1], (float)ra[2], (float)ra[3]};
                float4 f1 = {(float)ra[4], (float)ra[5], (float)ra[6], (float)ra[7]};
                float* op = out + (long)(pair * 4 + u * 2 + ey) * 64 + efg * 8;
                *(float4*)op = f0;
                *(float4*)(op + 4) = f1;
            }
        }
    }
#undef WFRAG
}

extern "C" void kernel_launch(void* const* d_in, const int* in_sizes, int n_in,
                              void* d_out, int out_size, void* d_ws, size_t ws_size,
                              hipStream_t stream) {
    (void)in_sizes; (void)n_in; (void)ws_size; (void)out_size;
    _Float16* x16 = (_Float16*)d_ws;

    prep_x<<<(NX * 16 + 255) / 256, 256, 0, stream>>>((const float*)d_in[0], x16);

    pointnet_fused<<<GRID, BLOCK, 0, stream>>>(
        x16,
        (const float*)d_in[1],   // pos_x
        (const float*)d_in[2],   // pos_y
        (const int*)  d_in[3],   // x_idx
        (const float*)d_in[5],  (const float*)d_in[6],   // W0a, b0a
        (const float*)d_in[7],  (const float*)d_in[8],   // W1a, b1a
        (const float*)d_in[9],                            // Wsa
        (const float*)d_in[10], (const float*)d_in[11],  // W0b, b0b
        (const float*)d_in[12], (const float*)d_in[13],  // W1b, b1b
        (float*)d_out);
}